// Round 1
// baseline (1221.272 us; speedup 1.0000x reference)
//
#include <hip/hip_runtime.h>
#include <hip/hip_bf16.h>
#include <cstdint>

// Model constants
#define B_     128
#define P_     168
#define HIDC_  32
#define CK_    6
#define L_     163      // P - CK + 1
#define K_     4032     // P * M1*M2*M3
#define NOUT_  32256    // P * HIDC * CK
#define NKC_   126      // K_/32 chunks

typedef __attribute__((ext_vector_type(8))) short short8;
typedef __attribute__((ext_vector_type(4))) float floatx4;

__device__ __forceinline__ unsigned short f2bf(float f) {
  unsigned int u = __float_as_uint(f);
  return (unsigned short)((u + 0x7FFFu + ((u >> 16) & 1u)) >> 16);  // RNE
}
__device__ __forceinline__ short8 cvt8(float4 f0, float4 f1) {
  short8 r;
  r[0] = (short)f2bf(f0.x); r[1] = (short)f2bf(f0.y);
  r[2] = (short)f2bf(f0.z); r[3] = (short)f2bf(f0.w);
  r[4] = (short)f2bf(f1.x); r[5] = (short)f2bf(f1.y);
  r[6] = (short)f2bf(f1.z); r[7] = (short)f2bf(f1.w);
  return r;
}
__device__ __forceinline__ float sigm(float x) { return 1.f / (1.f + __expf(-x)); }

// ---------------------------------------------------------------------------
// K0: pack x (fp32) into MFMA A-fragment layout, bf16.
// A-frag layout for 16x16x32: m = lane&15, k = (lane>>4)*8 + j.
// Flat index: (((kc*8 + mtile)*64 + lane) * 8 + j)
__global__ void prep_k(const float* __restrict__ x, unsigned short* __restrict__ Apack) {
  int idx = blockIdx.x * 256 + threadIdx.x;          // 128*4032 = 516096 exactly
  int b = idx / K_;
  int k = idx - b * K_;
  unsigned short v = f2bf(x[idx]);
  int kc = k >> 5, qq = (k >> 3) & 3, j = k & 7, mt = b >> 4, r = b & 15;
  Apack[(size_t)(((kc * 8 + mt) * 64) + qq * 16 + r) * 8 + j] = v;
}

// ---------------------------------------------------------------------------
// K1: C[b][o] = relu( sum_k x[b][k]*W[o][k] + bias[o] )   (bf16 MFMA, fp32 acc)
// Block: 256 thr = 4 waves; each wave computes 128(M) x 16(N); block covers 64 N.
__global__ __launch_bounds__(256, 2) void gemm_k(const short8* __restrict__ Ap,
    const float* __restrict__ W, const float* __restrict__ bias,
    float* __restrict__ C) {
  const int lane = threadIdx.x & 63;
  const int wave = threadIdx.x >> 6;
  const int q = lane >> 4;
  const int n = blockIdx.x * 64 + wave * 16 + (lane & 15);
  const float* wp = W + (size_t)n * K_ + q * 8;

  floatx4 zero = {0.f, 0.f, 0.f, 0.f};
  floatx4 acc[8];
#pragma unroll
  for (int i = 0; i < 8; i++) acc[i] = zero;

  // B-frag for chunk 0 (8 consecutive fp32 per lane -> bf16)
  float4 g0 = *(const float4*)(wp);
  float4 g1 = *(const float4*)(wp + 4);
  short8 bfrag = cvt8(g0, g1);

  for (int kc = 0; kc < NKC_ - 1; kc++) {
    short8 a[8];
    const short8* af = Ap + (size_t)kc * 512 + lane;
#pragma unroll
    for (int mt = 0; mt < 8; mt++) a[mt] = af[mt * 64];
    // prefetch next B chunk (HBM) while MFMAing current
    float4 h0 = *(const float4*)(wp + (size_t)(kc + 1) * 32);
    float4 h1 = *(const float4*)(wp + (size_t)(kc + 1) * 32 + 4);
#pragma unroll
    for (int mt = 0; mt < 8; mt++)
      acc[mt] = __builtin_amdgcn_mfma_f32_16x16x32_bf16(a[mt], bfrag, acc[mt], 0, 0, 0);
    bfrag = cvt8(h0, h1);
  }
  {
    short8 a[8];
    const short8* af = Ap + (size_t)(NKC_ - 1) * 512 + lane;
#pragma unroll
    for (int mt = 0; mt < 8; mt++) a[mt] = af[mt * 64];
#pragma unroll
    for (int mt = 0; mt < 8; mt++)
      acc[mt] = __builtin_amdgcn_mfma_f32_16x16x32_bf16(a[mt], bfrag, acc[mt], 0, 0, 0);
  }

  // Epilogue: D row = (lane>>4)*4 + reg (= batch), col = lane&15 (= n). +bias, relu.
  float bv = bias[n];
#pragma unroll
  for (int mt = 0; mt < 8; mt++) {
#pragma unroll
    for (int r = 0; r < 4; r++) {
      int brow = mt * 16 + q * 4 + r;
      float v = acc[mt][r] + bv;
      C[(size_t)brow * NOUT_ + n] = v > 0.f ? v : 0.f;
    }
  }
}

// ---------------------------------------------------------------------------
// K2: diagonal sum: c2[b][h][l] = sum_{k<6} Crelu[b][h*1008 + k*168 + (k+l)]
__global__ void diag_k(const float* __restrict__ C, float* __restrict__ c2) {
  int idx = blockIdx.x * 256 + threadIdx.x;          // 128*32*163 = 667648 exactly
  int l = idx % 163;
  int t = idx / 163;
  int h = t % 32;
  int b = t / 32;
  const float* base = C + (size_t)b * NOUT_ + h * 1008 + l;
  float s = 0.f;
#pragma unroll
  for (int k = 0; k < 6; k++) s += base[k * 169];    // k*168 + k
  c2[idx] = s;
}

// ---------------------------------------------------------------------------
// K3: recurrent kernel. Blocks 0..127: GRU1 (one batch row each, 163 steps).
//     Blocks 128..137: skip-GRU (one thread per row, 3072 rows, 6 steps).
__global__ __launch_bounds__(320) void recur_k(const float* __restrict__ c2,
    const float* __restrict__ W1ih, const float* __restrict__ W1hh,
    const float* __restrict__ b1ih, const float* __restrict__ b1hh,
    const float* __restrict__ Wsih, const float* __restrict__ Wshh,
    const float* __restrict__ bsih, const float* __restrict__ bshh,
    float* __restrict__ r_out, float* __restrict__ hs_out) {
  int tid = threadIdx.x;
  if (blockIdx.x < 128) {
    __shared__ float xl[32 * 163];
    __shared__ float hsh[100], rsh[100], zsh[100];
    int b = blockIdx.x;
    for (int i = tid; i < 32 * 163; i += 320) xl[i] = c2[b * 5216 + i];
    if (tid < 100) hsh[tid] = 0.f;
    float wih[32], whh[100], bi = 0.f, bh = 0.f;
    if (tid < 300) {
      bi = b1ih[tid]; bh = b1hh[tid];
#pragma unroll
      for (int i = 0; i < 32; i++) wih[i] = W1ih[tid * 32 + i];
#pragma unroll
      for (int i = 0; i < 100; i++) whh[i] = W1hh[tid * 100 + i];
    }
    __syncthreads();
    for (int t = 0; t < 163; t++) {
      float gi = bi, gh = bh;
      if (tid < 300) {
#pragma unroll
        for (int i = 0; i < 32; i++) gi += wih[i] * xl[i * 163 + t];
#pragma unroll
        for (int i = 0; i < 100; i++) gh += whh[i] * hsh[i];
        if (tid < 100) rsh[tid] = sigm(gi + gh);
        else if (tid < 200) zsh[tid - 100] = sigm(gi + gh);
      }
      __syncthreads();
      if (tid >= 200 && tid < 300) {
        int i = tid - 200;
        float nn = tanhf(gi + rsh[i] * gh);   // gi=inn(+bih_n), gh=hn(+bhh_n)
        float z = zsh[i];
        hsh[i] = (1.f - z) * nn + z * hsh[i];
      }
      __syncthreads();
    }
    if (tid < 100) r_out[b * 100 + tid] = hsh[tid];
  } else {
    __shared__ float wi[480], wh[75], bi2[15], bh2[15];
    for (int i = tid; i < 480; i += 320) wi[i] = Wsih[i];
    if (tid < 75) wh[tid] = Wshh[tid];
    if (tid < 15) { bi2[tid] = bsih[tid]; bh2[tid] = bshh[tid]; }
    __syncthreads();
    int row = (blockIdx.x - 128) * 320 + tid;
    if (row < 3072) {
      int b = row / 24, sk = row - b * 24;
      float h[5] = {0.f, 0.f, 0.f, 0.f, 0.f};
      for (int t = 0; t < 6; t++) {
        int l = 19 + t * 24 + sk;
        float xv[32];
#pragma unroll
        for (int c = 0; c < 32; c++) xv[c] = c2[(size_t)(b * 32 + c) * 163 + l];
        float gi[15], gh[15];
#pragma unroll
        for (int g = 0; g < 15; g++) {
          float s = bi2[g];
#pragma unroll
          for (int c = 0; c < 32; c++) s += wi[g * 32 + c] * xv[c];
          gi[g] = s;
          float s2 = bh2[g];
#pragma unroll
          for (int c = 0; c < 5; c++) s2 += wh[g * 5 + c] * h[c];
          gh[g] = s2;
        }
#pragma unroll
        for (int i = 0; i < 5; i++) {
          float r = sigm(gi[i] + gh[i]);
          float z = sigm(gi[5 + i] + gh[5 + i]);
          float nn = tanhf(gi[10 + i] + r * gh[10 + i]);
          h[i] = (1.f - z) * nn + z * h[i];
        }
      }
#pragma unroll
      for (int i = 0; i < 5; i++) hs_out[b * 120 + sk * 5 + i] = h[i];
    }
  }
}

// ---------------------------------------------------------------------------
// K4: final linear + highway + sigmoid. One thread per (b,m), 3072 total.
__global__ void final_k(const float* __restrict__ x, const float* __restrict__ r_in,
    const float* __restrict__ hs, const float* __restrict__ lw,
    const float* __restrict__ lb, const float* __restrict__ hww,
    const float* __restrict__ hwb, float* __restrict__ out) {
  int idx = blockIdx.x * 256 + threadIdx.x;          // 3072 exactly
  int b = idx / 24, m = idx - (idx / 24) * 24;
  float acc = lb[m] + hwb[0];
  const float* wrow = lw + m * 220;
#pragma unroll 4
  for (int i = 0; i < 100; i++) acc += r_in[b * 100 + i] * wrow[i];
#pragma unroll 4
  for (int i = 0; i < 120; i++) acc += hs[b * 120 + i] * wrow[100 + i];
#pragma unroll
  for (int t = 0; t < 24; t++) acc += x[(size_t)b * K_ + (144 + t) * 24 + m] * hww[t];
  out[idx] = sigm(acc);
}

// ---------------------------------------------------------------------------
extern "C" void kernel_launch(void* const* d_in, const int* in_sizes, int n_in,
                              void* d_out, int out_size, void* d_ws, size_t ws_size,
                              hipStream_t stream) {
  const float* x      = (const float*)d_in[0];
  const float* conv_w = (const float*)d_in[1];
  const float* conv_b = (const float*)d_in[2];
  const float* g1Wih  = (const float*)d_in[3];
  const float* g1Whh  = (const float*)d_in[4];
  const float* g1bih  = (const float*)d_in[5];
  const float* g1bhh  = (const float*)d_in[6];
  const float* gsWih  = (const float*)d_in[7];
  const float* gsWhh  = (const float*)d_in[8];
  const float* gsbih  = (const float*)d_in[9];
  const float* gsbhh  = (const float*)d_in[10];
  const float* lw     = (const float*)d_in[11];
  const float* lb     = (const float*)d_in[12];
  const float* hww    = (const float*)d_in[13];
  const float* hwb    = (const float*)d_in[14];
  float* out = (float*)d_out;

  char* ws = (char*)d_ws;
  // ws layout (bytes): Apack [0, 1.0MB) | Crelu [1MB, 17.56MB) | c2 | r | hs  (~20.4MB)
  unsigned short* Apack = (unsigned short*)(ws);
  float* Cbuf  = (float*)(ws + (size_t)1048576);
  float* c2    = (float*)(ws + (size_t)17563648);
  float* r_out = (float*)(ws + (size_t)20234240);
  float* hs    = (float*)(ws + (size_t)20285440);

  prep_k <<<2016, 256, 0, stream>>>(x, Apack);
  gemm_k <<<504,  256, 0, stream>>>((const short8*)Apack, conv_w, conv_b, Cbuf);
  diag_k <<<2608, 256, 0, stream>>>(Cbuf, c2);
  recur_k<<<138,  320, 0, stream>>>(c2, g1Wih, g1Whh, g1bih, g1bhh,
                                    gsWih, gsWhh, gsbih, gsbhh, r_out, hs);
  final_k<<<12,   256, 0, stream>>>(x, r_out, hs, lw, lb, hww, hwb, out);
}

// Round 2
// 1013.749 us; speedup vs baseline: 1.2047x; 1.2047x over previous
//
#include <hip/hip_runtime.h>
#include <hip/hip_bf16.h>
#include <cstdint>

#define B_      128
#define K_      4032
#define NOUT_   32256
#define NCHUNK_ 126          // K_/32
#define CSTRIDE 4128768ull   // 128*32256 floats per partial-C buffer

typedef __attribute__((ext_vector_type(8))) short short8;
typedef __attribute__((ext_vector_type(4))) float floatx4;

__device__ __forceinline__ unsigned short f2bf(float f) {
  unsigned int u = __float_as_uint(f);
  return (unsigned short)((u + 0x7FFFu + ((u >> 16) & 1u)) >> 16);  // RNE
}
__device__ __forceinline__ short8 cvt8(float4 f0, float4 f1) {
  short8 r;
  r[0] = (short)f2bf(f0.x); r[1] = (short)f2bf(f0.y);
  r[2] = (short)f2bf(f0.z); r[3] = (short)f2bf(f0.w);
  r[4] = (short)f2bf(f1.x); r[5] = (short)f2bf(f1.y);
  r[6] = (short)f2bf(f1.z); r[7] = (short)f2bf(f1.w);
  return r;
}
__device__ __forceinline__ float sigm(float x) { return 1.f / (1.f + __expf(-x)); }

__device__ __forceinline__ void gl_lds16(const void* g, void* l) {
  __builtin_amdgcn_global_load_lds(
      (const __attribute__((address_space(1))) void*)g,
      (__attribute__((address_space(3))) void*)l, 16, 0, 0);
}

// ---------------------------------------------------------------------------
// K0: pack x (fp32) into MFMA A-fragment layout, bf16.
__global__ void prep_k(const float* __restrict__ x, unsigned short* __restrict__ Apack) {
  int idx = blockIdx.x * 256 + threadIdx.x;          // 128*4032 = 516096 exactly
  int b = idx / K_;
  int k = idx - b * K_;
  unsigned short v = f2bf(x[idx]);
  int kc = k >> 5, qq = (k >> 3) & 3, j = k & 7, mt = b >> 4, r = b & 15;
  Apack[(size_t)(((kc * 8 + mt) * 64) + qq * 16 + r) * 8 + j] = v;
}

// ---------------------------------------------------------------------------
// K1: LDS-staged K-split GEMM. Block = 256 thr (4 waves), tile 128M x 128N,
// K-slice = kchunks*32. Wave w: 128M x 32N (2 ntiles), A-frags reused across nt.
// W staged fp32 via global_load_lds with XOR-swizzled [n][quad^ (n&7)] layout
// (8 rows x 128B contiguous per stage instr; bank-balanced b128 reads).
__global__ __launch_bounds__(256, 3) void gemm_k(const unsigned short* __restrict__ Ap,
    const float* __restrict__ W, float* __restrict__ Cpart, int kchunks) {
  __shared__ unsigned short Albs[2][4096];  // 2 x 8KB bf16 A-chunk (linear frag order)
  __shared__ float4 Wlds[2][1024];          // 2 x 16KB fp32 W-chunk (swizzled)

  const int tid  = threadIdx.x;
  const int lane = tid & 63;
  const int w    = tid >> 6;
  const int q    = lane >> 4;
  const int l7   = lane & 7;

  const int slice = blockIdx.x / 252;
  const int n0    = (blockIdx.x - slice * 252) * 128;
  const int kbase = slice * kchunks;

  floatx4 zero = {0.f, 0.f, 0.f, 0.f};
  floatx4 acc[8][2];
#pragma unroll
  for (int mt = 0; mt < 8; mt++) { acc[mt][0] = zero; acc[mt][1] = zero; }

  // staging lambda: chunk kc_glob -> buffer buf
  auto stage = [&](int buf, int kc_glob) {
    // A: 8KB = 8 instrs of 1KB; wave w does j = 2w, 2w+1
#pragma unroll
    for (int i = 0; i < 2; i++) {
      int j = w * 2 + i;
      const char* g = (const char*)Ap + (size_t)kc_glob * 8192 + j * 1024 + lane * 16;
      gl_lds16(g, (char*)Albs[buf] + j * 1024);
    }
    // W: 16KB = 16 instrs; wave w does j = 4w..4w+3. Lane: row nloc=j*8+(lane>>3),
    // quad=(lane&7)^((lane>>3)&7); lands at slot s=j*64+lane = nloc*8 + (quad^(nloc&7)).
#pragma unroll
    for (int i = 0; i < 4; i++) {
      int j = w * 4 + i;
      int nloc = j * 8 + (lane >> 3);
      int quad = (lane & 7) ^ ((lane >> 3) & 7);
      const float* g = W + (size_t)(n0 + nloc) * K_ + kc_glob * 32 + quad * 4;
      gl_lds16(g, &Wlds[buf][j * 64]);
    }
  };

  stage(0, kbase);
  __syncthreads();

  for (int kc = 0; kc < kchunks; kc++) {
    int pb = kc & 1;
    if (kc + 1 < kchunks) stage(pb ^ 1, kbase + kc + 1);

    short8 a[8];
    const short8* Ab = (const short8*)Albs[pb];
#pragma unroll
    for (int mt = 0; mt < 8; mt++) a[mt] = Ab[mt * 64 + lane];

    short8 bf[2];
    const float4* Wb = Wlds[pb];
#pragma unroll
    for (int nt = 0; nt < 2; nt++) {
      int n = w * 32 + nt * 16 + (lane & 15);
      float4 lo = Wb[n * 8 + ((2 * q) ^ l7)];
      float4 hi = Wb[n * 8 + ((2 * q + 1) ^ l7)];
      bf[nt] = cvt8(lo, hi);
    }
#pragma unroll
    for (int mt = 0; mt < 8; mt++) {
#pragma unroll
      for (int nt = 0; nt < 2; nt++)
        acc[mt][nt] = __builtin_amdgcn_mfma_f32_16x16x32_bf16(a[mt], bf[nt], acc[mt][nt], 0, 0, 0);
    }
    __syncthreads();
  }

  // Epilogue: D row=(lane>>4)*4+reg (batch), col=lane&15 (n). Raw partial (no bias).
  float* Cp = Cpart + (size_t)slice * CSTRIDE;
#pragma unroll
  for (int mt = 0; mt < 8; mt++) {
#pragma unroll
    for (int nt = 0; nt < 2; nt++) {
      int n = n0 + w * 32 + nt * 16 + (lane & 15);
#pragma unroll
      for (int r = 0; r < 4; r++) {
        int brow = mt * 16 + q * 4 + r;
        Cp[(size_t)brow * NOUT_ + n] = acc[mt][nt][r];
      }
    }
  }
}

// ---------------------------------------------------------------------------
// K2: sum K-partials + bias, relu, then diagonal sum over CK.
__global__ void diag_k(const float* __restrict__ Cp, const float* __restrict__ bias,
                       float* __restrict__ c2, int nparts) {
  int idx = blockIdx.x * 256 + threadIdx.x;          // 128*32*163 = 667648 exactly
  int l = idx % 163;
  int t = idx / 163;
  int h = t % 32;
  int b = t / 32;
  size_t base = (size_t)b * NOUT_ + h * 1008 + l;
  int obase = h * 1008 + l;
  float s = 0.f;
#pragma unroll
  for (int k = 0; k < 6; k++) {
    float v = bias[obase + k * 169];
    for (int p = 0; p < nparts; p++) v += Cp[(size_t)p * CSTRIDE + base + k * 169];
    s += fmaxf(v, 0.f);
  }
  c2[idx] = s;
}

// ---------------------------------------------------------------------------
// K3: recurrent kernel. Blocks 0..127: GRU1 (one batch row, 163 steps).
//     Blocks 128..137: skip-GRU (thread-per-row, 3072 rows, 6 steps).
__global__ __launch_bounds__(320) void recur_k(const float* __restrict__ c2,
    const float* __restrict__ W1ih, const float* __restrict__ W1hh,
    const float* __restrict__ b1ih, const float* __restrict__ b1hh,
    const float* __restrict__ Wsih, const float* __restrict__ Wshh,
    const float* __restrict__ bsih, const float* __restrict__ bshh,
    float* __restrict__ r_out, float* __restrict__ hs_out) {
  int tid = threadIdx.x;
  if (blockIdx.x < 128) {
    __shared__ float xl[163 * 32];                 // transposed: [t][c]
    __shared__ float hsh[100], rsh[100], zsh[100];
    int b = blockIdx.x;
    for (int i = tid; i < 5216; i += 320) {
      int c = i / 163, t = i - c * 163;
      xl[t * 32 + c] = c2[b * 5216 + i];
    }
    if (tid < 100) hsh[tid] = 0.f;
    float4 wi4[8], wh4[25];
    float bi = 0.f, bh = 0.f;
    if (tid < 300) {
      bi = b1ih[tid]; bh = b1hh[tid];
      const float4* p = (const float4*)(W1ih + tid * 32);
#pragma unroll
      for (int i = 0; i < 8; i++) wi4[i] = p[i];
      const float4* p2 = (const float4*)(W1hh + tid * 100);
#pragma unroll
      for (int i = 0; i < 25; i++) wh4[i] = p2[i];
    }
    __syncthreads();
    for (int t = 0; t < 163; t++) {
      float gi = 0.f, gh = 0.f;
      if (tid < 300) {
        const float4* xt = (const float4*)(xl + t * 32);
        float4 A0 = {0, 0, 0, 0}, A1 = {0, 0, 0, 0};
#pragma unroll
        for (int i = 0; i < 4; i++) A0 += wi4[i] * xt[i];
#pragma unroll
        for (int i = 4; i < 8; i++) A1 += wi4[i] * xt[i];
        float4 Ai = A0 + A1;
        gi = bi + Ai.x + Ai.y + Ai.z + Ai.w;
        const float4* h4 = (const float4*)hsh;
        float4 H0 = {0, 0, 0, 0}, H1 = {0, 0, 0, 0};
#pragma unroll
        for (int i = 0; i < 12; i++) H0 += wh4[i] * h4[i];
#pragma unroll
        for (int i = 12; i < 25; i++) H1 += wh4[i] * h4[i];
        float4 Hh = H0 + H1;
        gh = bh + Hh.x + Hh.y + Hh.z + Hh.w;
        if (tid < 100) rsh[tid] = sigm(gi + gh);
        else if (tid < 200) zsh[tid - 100] = sigm(gi + gh);
      }
      __syncthreads();
      if (tid >= 200 && tid < 300) {
        int i = tid - 200;
        float nn = tanhf(gi + rsh[i] * gh);
        float z = zsh[i];
        hsh[i] = (1.f - z) * nn + z * hsh[i];
      }
      __syncthreads();
    }
    if (tid < 100) r_out[b * 100 + tid] = hsh[tid];
  } else {
    __shared__ float wi[480], wh[75], bi2[15], bh2[15];
    for (int i = tid; i < 480; i += 320) wi[i] = Wsih[i];
    if (tid < 75) wh[tid] = Wshh[tid];
    if (tid < 15) { bi2[tid] = bsih[tid]; bh2[tid] = bshh[tid]; }
    __syncthreads();
    int row = (blockIdx.x - 128) * 320 + tid;
    if (row < 3072) {
      int b = row / 24, sk = row - b * 24;
      float h[5] = {0.f, 0.f, 0.f, 0.f, 0.f};
      for (int t = 0; t < 6; t++) {
        int l = 19 + t * 24 + sk;
        float xv[32];
#pragma unroll
        for (int c = 0; c < 32; c++) xv[c] = c2[(size_t)(b * 32 + c) * 163 + l];
        float gi[15], gh[15];
#pragma unroll
        for (int g = 0; g < 15; g++) {
          float s = bi2[g];
#pragma unroll
          for (int c = 0; c < 32; c++) s += wi[g * 32 + c] * xv[c];
          gi[g] = s;
          float s2 = bh2[g];
#pragma unroll
          for (int c = 0; c < 5; c++) s2 += wh[g * 5 + c] * h[c];
          gh[g] = s2;
        }
#pragma unroll
        for (int i = 0; i < 5; i++) {
          float r = sigm(gi[i] + gh[i]);
          float z = sigm(gi[5 + i] + gh[5 + i]);
          float nn = tanhf(gi[10 + i] + r * gh[10 + i]);
          h[i] = (1.f - z) * nn + z * h[i];
        }
      }
#pragma unroll
      for (int i = 0; i < 5; i++) hs_out[b * 120 + sk * 5 + i] = h[i];
    }
  }
}

// ---------------------------------------------------------------------------
// K4: final linear + highway + sigmoid. One thread per (b,m), 3072 total.
__global__ void final_k(const float* __restrict__ x, const float* __restrict__ r_in,
    const float* __restrict__ hs, const float* __restrict__ lw,
    const float* __restrict__ lb, const float* __restrict__ hww,
    const float* __restrict__ hwb, float* __restrict__ out) {
  int idx = blockIdx.x * 256 + threadIdx.x;          // 3072 exactly
  int b = idx / 24, m = idx - (idx / 24) * 24;
  float acc = lb[m] + hwb[0];
  const float* wrow = lw + m * 220;
#pragma unroll 4
  for (int i = 0; i < 100; i++) acc += r_in[b * 100 + i] * wrow[i];
#pragma unroll 4
  for (int i = 0; i < 120; i++) acc += hs[b * 120 + i] * wrow[100 + i];
#pragma unroll
  for (int t = 0; t < 24; t++) acc += x[(size_t)b * K_ + (144 + t) * 24 + m] * hww[t];
  out[idx] = sigm(acc);
}

// ---------------------------------------------------------------------------
extern "C" void kernel_launch(void* const* d_in, const int* in_sizes, int n_in,
                              void* d_out, int out_size, void* d_ws, size_t ws_size,
                              hipStream_t stream) {
  const float* x      = (const float*)d_in[0];
  const float* conv_w = (const float*)d_in[1];
  const float* conv_b = (const float*)d_in[2];
  const float* g1Wih  = (const float*)d_in[3];
  const float* g1Whh  = (const float*)d_in[4];
  const float* g1bih  = (const float*)d_in[5];
  const float* g1bhh  = (const float*)d_in[6];
  const float* gsWih  = (const float*)d_in[7];
  const float* gsWhh  = (const float*)d_in[8];
  const float* gsbih  = (const float*)d_in[9];
  const float* gsbhh  = (const float*)d_in[10];
  const float* lw     = (const float*)d_in[11];
  const float* lb     = (const float*)d_in[12];
  const float* hww    = (const float*)d_in[13];
  const float* hwb    = (const float*)d_in[14];
  float* out = (float*)d_out;

  // K-split factor: 3 if workspace allows (3 partial-C buffers), else 1.
  const int nslice = (ws_size >= 53377024ull) ? 3 : 1;
  const int kchunks = NCHUNK_ / nslice;

  char* ws = (char*)d_ws;
  unsigned short* Apack = (unsigned short*)ws;
  size_t off = 1048576;
  float* Cpart = (float*)(ws + off); off += (size_t)nslice * 16515072ull;
  float* c2    = (float*)(ws + off); off += 2670592;
  float* r_out = (float*)(ws + off); off += 51200;
  float* hs    = (float*)(ws + off);

  prep_k <<<2016, 256, 0, stream>>>(x, Apack);
  gemm_k <<<252 * nslice, 256, 0, stream>>>(Apack, conv_w, Cpart, kchunks);
  diag_k <<<2608, 256, 0, stream>>>(Cpart, conv_b, c2, nslice);
  recur_k<<<138,  320, 0, stream>>>(c2, g1Wih, g1Whh, g1bih, g1bhh,
                                    gsWih, gsWhh, gsbih, gsbhh, r_out, hs);
  final_k<<<12,   256, 0, stream>>>(x, r_out, hs, lw, lb, hww, hwb, out);
}

// Round 3
// 909.976 us; speedup vs baseline: 1.3421x; 1.1140x over previous
//
#include <hip/hip_runtime.h>
#include <hip/hip_bf16.h>
#include <cstdint>

#define B_      128
#define K_      4032
#define NOUT_   32256
#define CSTRIDE 4128768ull   // 128*32256 floats per partial-C buffer
#define NSLICE  3
#define KCH     42           // 126/3 chunks per slice
#define GIROWS  20864        // 128*163
#define NTILES_GI 19         // ceil(300/16)

typedef __attribute__((ext_vector_type(8))) short short8;
typedef __attribute__((ext_vector_type(4))) float floatx4;

__device__ __forceinline__ unsigned short f2bf(float f) {
  unsigned int u = __float_as_uint(f);
  return (unsigned short)((u + 0x7FFFu + ((u >> 16) & 1u)) >> 16);  // RNE
}
__device__ __forceinline__ short8 cvt8(float4 f0, float4 f1) {
  short8 r;
  r[0] = (short)f2bf(f0.x); r[1] = (short)f2bf(f0.y);
  r[2] = (short)f2bf(f0.z); r[3] = (short)f2bf(f0.w);
  r[4] = (short)f2bf(f1.x); r[5] = (short)f2bf(f1.y);
  r[6] = (short)f2bf(f1.z); r[7] = (short)f2bf(f1.w);
  return r;
}
__device__ __forceinline__ float sigm(float x) { return 1.f / (1.f + __expf(-x)); }
__device__ __forceinline__ float tanh_f(float x) {
  x = fminf(fmaxf(x, -15.f), 15.f);
  float e = __expf(2.f * x);
  return (e - 1.f) / (e + 1.f);
}
__device__ __forceinline__ void gl_lds16(const void* g, void* l) {
  __builtin_amdgcn_global_load_lds(
      (const __attribute__((address_space(1))) void*)g,
      (__attribute__((address_space(3))) void*)l, 16, 0, 0);
}

// ---------------------------------------------------------------------------
// K0: pack x (fp32) into MFMA A-fragment layout, bf16.
__global__ void prep_k(const float* __restrict__ x, unsigned short* __restrict__ Apack) {
  int idx = blockIdx.x * 256 + threadIdx.x;          // 128*4032 = 516096 exactly
  int b = idx / K_;
  int k = idx - b * K_;
  unsigned short v = f2bf(x[idx]);
  int kc = k >> 5, qq = (k >> 3) & 3, j = k & 7, mt = b >> 4, r = b & 15;
  Apack[(size_t)(((kc * 8 + mt) * 64) + qq * 16 + r) * 8 + j] = v;
}

// ---------------------------------------------------------------------------
// K0b: pack Wih (300x32 fp32) into B-fragment bf16 layout (19 n-tiles).
__global__ void bpack_k(const float* __restrict__ Wih, unsigned short* __restrict__ Bp) {
  int t = blockIdx.x * 256 + threadIdx.x;            // 19*64*8 = 9728
  if (t >= NTILES_GI * 64 * 8) return;
  int j = t & 7, slot = t >> 3;
  int lane = slot & 63, nt = slot >> 6;
  int n = nt * 16 + (lane & 15);
  int k = (lane >> 4) * 8 + j;
  Bp[t] = (n < 300) ? f2bf(Wih[n * 32 + k]) : (unsigned short)0;
}

// ---------------------------------------------------------------------------
// K1: K-split GEMM. Block = 256 thr (4 waves), tile 128M x 64N.
// A-frags read directly from global (1MB, L2-resident). W double-buffered in
// 16KB LDS via global_load_lds (XOR-swizzled). 1512 blocks, ~5/CU.
__global__ __launch_bounds__(256, 5) void gemm_k(const unsigned short* __restrict__ Ap,
    const float* __restrict__ W, float* __restrict__ Cpart) {
  __shared__ float4 Wlds[2][512];                    // 2 x 8KB

  const int tid  = threadIdx.x;
  const int lane = tid & 63;
  const int w    = tid >> 6;
  const int q    = lane >> 4;

  const int slice = blockIdx.x / 504;
  const int nb    = blockIdx.x - slice * 504;
  const int n0    = nb * 64;
  const int kbase = slice * KCH;

  floatx4 zero = {0.f, 0.f, 0.f, 0.f};
  floatx4 acc[8];
#pragma unroll
  for (int i = 0; i < 8; i++) acc[i] = zero;

  const int nloc_lo = lane >> 3;
  const int quad_st = (lane & 7) ^ ((lane >> 3) & 7);

  auto stage = [&](int buf, int kcg) {
#pragma unroll
    for (int i = 0; i < 2; i++) {
      int j = w * 2 + i;
      int nloc = j * 8 + nloc_lo;
      const float* g = W + (size_t)(n0 + nloc) * K_ + kcg * 32 + quad_st * 4;
      gl_lds16(g, &Wlds[buf][j * 64]);
    }
  };

  stage(0, kbase);
  __syncthreads();

  const int nl  = w * 16 + (lane & 15);
  const int sw0 = nl * 8 + ((2 * q)     ^ (nl & 7));
  const int sw1 = nl * 8 + ((2 * q + 1) ^ (nl & 7));

  for (int kc = 0; kc < KCH; kc++) {
    int pb = kc & 1;
    if (kc + 1 < KCH) stage(pb ^ 1, kbase + kc + 1);

    const short8* Ag = (const short8*)Ap + (size_t)(kbase + kc) * 512 + lane;
    short8 a[8];
#pragma unroll
    for (int mt = 0; mt < 8; mt++) a[mt] = Ag[mt * 64];

    float4 lo = Wlds[pb][sw0];
    float4 hi = Wlds[pb][sw1];
    short8 bfr = cvt8(lo, hi);
#pragma unroll
    for (int mt = 0; mt < 8; mt++)
      acc[mt] = __builtin_amdgcn_mfma_f32_16x16x32_bf16(a[mt], bfr, acc[mt], 0, 0, 0);
    __syncthreads();
  }

  float* Cp = Cpart + (size_t)slice * CSTRIDE;
  const int n = n0 + nl;
#pragma unroll
  for (int mt = 0; mt < 8; mt++) {
#pragma unroll
    for (int r = 0; r < 4; r++) {
      int brow = mt * 16 + q * 4 + r;
      Cp[(size_t)brow * NOUT_ + n] = acc[mt][r];
    }
  }
}

// ---------------------------------------------------------------------------
// K2: sum K-partials + bias, relu, diagonal sum; writes c2 fp32 AND the
// bf16 A-fragment pack for the gi GEMM (row = b*163+l, k = channel h).
__global__ void diag_k(const float* __restrict__ Cp, const float* __restrict__ bias,
                       float* __restrict__ c2, unsigned short* __restrict__ Xp) {
  int idx = blockIdx.x * 256 + threadIdx.x;          // 128*32*163 = 667648 exactly
  int l = idx % 163;
  int t = idx / 163;
  int h = t % 32;
  int b = t / 32;
  size_t base = (size_t)b * NOUT_ + h * 1008 + l;
  int obase = h * 1008 + l;
  float s = 0.f;
#pragma unroll
  for (int k = 0; k < 6; k++) {
    float v = bias[obase + k * 169];
#pragma unroll
    for (int p = 0; p < NSLICE; p++) v += Cp[(size_t)p * CSTRIDE + base + k * 169];
    s += fmaxf(v, 0.f);
  }
  c2[idx] = s;
  int row = b * 163 + l;
  int mt = row >> 4, r = row & 15, qq = h >> 3, j = h & 7;
  Xp[(size_t)((mt * 64) + qq * 16 + r) * 8 + j] = f2bf(s);
}

// ---------------------------------------------------------------------------
// K2b: gi GEMM: gi[row][g] = X[row] @ Wih[g] + bih[g] (+bhh[g] for r,z gates).
// One MFMA per wave-tile; A/B frags straight from global.
__global__ void gi_k(const unsigned short* __restrict__ Xp, const unsigned short* __restrict__ Bp,
                     const float* __restrict__ bih, const float* __restrict__ bhh,
                     float* __restrict__ gi) {
  int wid  = blockIdx.x * 4 + (threadIdx.x >> 6);    // 24776 wave-tiles
  int lane = threadIdx.x & 63;
  int mt = wid / NTILES_GI, nt = wid - mt * NTILES_GI;
  short8 a   = *(const short8*)(Xp + (size_t)(mt * 64 + lane) * 8);
  short8 bfr = *(const short8*)(Bp + (size_t)(nt * 64 + lane) * 8);
  floatx4 acc = {0.f, 0.f, 0.f, 0.f};
  acc = __builtin_amdgcn_mfma_f32_16x16x32_bf16(a, bfr, acc, 0, 0, 0);
  int n = nt * 16 + (lane & 15), q = lane >> 4;
  if (n < 300) {
    float bv = bih[n] + (n < 200 ? bhh[n] : 0.f);
#pragma unroll
    for (int r = 0; r < 4; r++) {
      int row = mt * 16 + q * 4 + r;
      gi[(size_t)row * 300 + n] = acc[r] + bv;
    }
  }
}

// ---------------------------------------------------------------------------
// K3: recurrences. Blocks 0..127: GRU1, one batch row each, 256 thr:
//   lane-pair (2u, 2u+1) owns hidden unit u; each half holds 52 cols of the
//   three Whh rows in regs; h broadcast from double-buffered LDS; halves
//   combined with shfl_xor(1); ONE barrier per step.
// Blocks 128..139: skip-GRU, thread-per-row (3072 rows, 6 steps).
__global__ __launch_bounds__(256, 1) void recur_k(const float* __restrict__ gi,
    const float* __restrict__ Whh, const float* __restrict__ bhh,
    const float* __restrict__ c2,
    const float* __restrict__ Wsih, const float* __restrict__ Wshh,
    const float* __restrict__ bsih, const float* __restrict__ bshh,
    float* __restrict__ r_out, float* __restrict__ hs_out) {
  int tid = threadIdx.x;
  if (blockIdx.x < 128) {
    __shared__ float hbuf[2][104];
    int b = blockIdx.x;
    bool active = tid < 200;
    int u = tid >> 1, half = tid & 1;

    float wreg[3][52];
    if (active) {
#pragma unroll
      for (int g = 0; g < 3; g++) {
        int grow = (g * 100 + u) * 100;
#pragma unroll
        for (int j = 0; j < 52; j++) {
          int col = half * 48 + j;
          float v = 0.f;
          if (half == 0 || j >= 4) v = Whh[grow + col];
          wreg[g][j] = v;
        }
      }
    }
    float bnh = (active && half == 0) ? bhh[200 + u] : 0.f;
    if (tid < 104) { hbuf[0][tid] = 0.f; }
    float hprev = 0.f;
    __syncthreads();

    const float* gib = gi + (size_t)b * 163 * 300;
    for (int t = 0; t < 163; t++) {
      int cur = t & 1, nxt = cur ^ 1;
      if (active) {
        float g0 = gib[t * 300 + u];
        float g1 = gib[t * 300 + 100 + u];
        float g2 = gib[t * 300 + 200 + u];
        const float4* hp = (const float4*)&hbuf[cur][half * 48];
        float s0 = 0.f, s1 = 0.f, s2 = bnh;
#pragma unroll
        for (int i = 0; i < 13; i++) {
          float4 hv = hp[i];
          s0 += wreg[0][4*i+0]*hv.x + wreg[0][4*i+1]*hv.y + wreg[0][4*i+2]*hv.z + wreg[0][4*i+3]*hv.w;
          s1 += wreg[1][4*i+0]*hv.x + wreg[1][4*i+1]*hv.y + wreg[1][4*i+2]*hv.z + wreg[1][4*i+3]*hv.w;
          s2 += wreg[2][4*i+0]*hv.x + wreg[2][4*i+1]*hv.y + wreg[2][4*i+2]*hv.z + wreg[2][4*i+3]*hv.w;
        }
        s0 += __shfl_xor(s0, 1);
        s1 += __shfl_xor(s1, 1);
        s2 += __shfl_xor(s2, 1);
        float r = sigm(g0 + s0);
        float z = sigm(g1 + s1);
        float n = tanh_f(g2 + r * s2);
        hprev = (1.f - z) * n + z * hprev;
        hbuf[nxt][u] = hprev;
      }
      __syncthreads();
    }
    if (active && half == 0) r_out[b * 100 + u] = hprev;
  } else {
    __shared__ float wi[480], wh[75], bi2[15], bh2[15];
    for (int i = tid; i < 480; i += 256) wi[i] = Wsih[i];
    if (tid < 75) wh[tid] = Wshh[tid];
    if (tid < 15) { bi2[tid] = bsih[tid]; bh2[tid] = bshh[tid]; }
    __syncthreads();
    int row = (blockIdx.x - 128) * 256 + tid;
    if (row < 3072) {
      int b = row / 24, sk = row - b * 24;
      float h[5] = {0.f, 0.f, 0.f, 0.f, 0.f};
      for (int t = 0; t < 6; t++) {
        int l = 19 + t * 24 + sk;
        float xv[32];
#pragma unroll
        for (int c = 0; c < 32; c++) xv[c] = c2[(size_t)(b * 32 + c) * 163 + l];
        float gv[15], gh[15];
#pragma unroll
        for (int g = 0; g < 15; g++) {
          float s = bi2[g];
#pragma unroll
          for (int c = 0; c < 32; c++) s += wi[g * 32 + c] * xv[c];
          gv[g] = s;
          float s2 = bh2[g];
#pragma unroll
          for (int c = 0; c < 5; c++) s2 += wh[g * 5 + c] * h[c];
          gh[g] = s2;
        }
#pragma unroll
        for (int i = 0; i < 5; i++) {
          float r = sigm(gv[i] + gh[i]);
          float z = sigm(gv[5 + i] + gh[5 + i]);
          float nn = tanh_f(gv[10 + i] + r * gh[10 + i]);
          h[i] = (1.f - z) * nn + z * h[i];
        }
      }
#pragma unroll
      for (int i = 0; i < 5; i++) hs_out[b * 120 + sk * 5 + i] = h[i];
    }
  }
}

// ---------------------------------------------------------------------------
// K4: final linear + highway + sigmoid. One thread per (b,m), 3072 total.
__global__ void final_k(const float* __restrict__ x, const float* __restrict__ r_in,
    const float* __restrict__ hs, const float* __restrict__ lw,
    const float* __restrict__ lb, const float* __restrict__ hww,
    const float* __restrict__ hwb, float* __restrict__ out) {
  int idx = blockIdx.x * 256 + threadIdx.x;          // 3072 exactly
  int b = idx / 24, m = idx - (idx / 24) * 24;
  float acc = lb[m] + hwb[0];
  const float* wrow = lw + m * 220;
#pragma unroll 4
  for (int i = 0; i < 100; i++) acc += r_in[b * 100 + i] * wrow[i];
#pragma unroll 4
  for (int i = 0; i < 120; i++) acc += hs[b * 120 + i] * wrow[100 + i];
#pragma unroll
  for (int t = 0; t < 24; t++) acc += x[(size_t)b * K_ + (144 + t) * 24 + m] * hww[t];
  out[idx] = sigm(acc);
}

// ---------------------------------------------------------------------------
extern "C" void kernel_launch(void* const* d_in, const int* in_sizes, int n_in,
                              void* d_out, int out_size, void* d_ws, size_t ws_size,
                              hipStream_t stream) {
  const float* x      = (const float*)d_in[0];
  const float* conv_w = (const float*)d_in[1];
  const float* conv_b = (const float*)d_in[2];
  const float* g1Wih  = (const float*)d_in[3];
  const float* g1Whh  = (const float*)d_in[4];
  const float* g1bih  = (const float*)d_in[5];
  const float* g1bhh  = (const float*)d_in[6];
  const float* gsWih  = (const float*)d_in[7];
  const float* gsWhh  = (const float*)d_in[8];
  const float* gsbih  = (const float*)d_in[9];
  const float* gsbhh  = (const float*)d_in[10];
  const float* lw     = (const float*)d_in[11];
  const float* lb     = (const float*)d_in[12];
  const float* hww    = (const float*)d_in[13];
  const float* hwb    = (const float*)d_in[14];
  float* out = (float*)d_out;

  char* ws = (char*)d_ws;
  size_t off = 0;
  auto alloc = [&](size_t bytes) { size_t cur = off; off = (off + bytes + 255) & ~255ull; return cur; };
  unsigned short* Apack = (unsigned short*)(ws + alloc(1032192));
  float* Cpart = (float*)(ws + alloc((size_t)NSLICE * CSTRIDE * 4));
  float* c2    = (float*)(ws + alloc(2670592));
  unsigned short* Xp = (unsigned short*)(ws + alloc(1335296));
  unsigned short* Bp = (unsigned short*)(ws + alloc(19456));
  float* gi    = (float*)(ws + alloc((size_t)GIROWS * 300 * 4));
  float* r_out = (float*)(ws + alloc(51200));
  float* hs    = (float*)(ws + alloc(15360));

  bpack_k<<<38,   256, 0, stream>>>(g1Wih, Bp);
  prep_k <<<2016, 256, 0, stream>>>(x, Apack);
  gemm_k <<<1512, 256, 0, stream>>>(Apack, conv_w, Cpart);
  diag_k <<<2608, 256, 0, stream>>>(Cpart, conv_b, c2, Xp);
  gi_k   <<<6194, 256, 0, stream>>>(Xp, Bp, g1bih, g1bhh, gi);
  recur_k<<<140,  256, 0, stream>>>(gi, g1Whh, g1bhh, c2,
                                    gsWih, gsWhh, gsbih, gsbhh, r_out, hs);
  final_k<<<12,   256, 0, stream>>>(x, r_out, hs, lw, lb, hww, hwb, out);
}